// Round 7
// baseline (964.834 us; speedup 1.0000x reference)
//
#include <hip/hip_runtime.h>
#include <hip/hip_bf16.h>

#define NN 50000
#define NE 600000
#define DIM 128
#define NEG 0.2f
#define GEPS 1e-16f

__device__ __forceinline__ float leaky(float x) { return x > 0.f ? x : NEG * x; }

// ---------------- CSR build ----------------
__global__ __launch_bounds__(256) void k_count(const int* __restrict__ d1,
                                               const int* __restrict__ d2,
                                               int* __restrict__ cnt, int netot) {
  int e = blockIdx.x * blockDim.x + threadIdx.x;
  if (e >= netot) return;
  int dst = (e < NE) ? d1[e] : d2[e - NE] + NN;
  atomicAdd(&cnt[dst], 1);
}

__global__ __launch_bounds__(1024) void k_scan1(const int* __restrict__ cnt,
                                                int* __restrict__ roff,
                                                int* __restrict__ partials, int nn) {
  __shared__ int part[1024];
  const int t = threadIdx.x;
  const int idx = blockIdx.x * 1024 + t;
  int v = (idx < nn) ? cnt[idx] : 0;
  part[t] = v;
  __syncthreads();
  for (int off = 1; off < 1024; off <<= 1) {
    int x = (t >= off) ? part[t - off] : 0;
    __syncthreads();
    part[t] += x;
    __syncthreads();
  }
  if (idx < nn) roff[idx] = part[t] - v;
  if (t == 1023) partials[blockIdx.x] = part[1023];
}

__global__ __launch_bounds__(128) void k_scan2(int* __restrict__ partials, int nb) {
  __shared__ int part[128];
  const int t = threadIdx.x;
  int v = (t < nb) ? partials[t] : 0;
  part[t] = v;
  __syncthreads();
  for (int off = 1; off < 128; off <<= 1) {
    int x = (t >= off) ? part[t - off] : 0;
    __syncthreads();
    part[t] += x;
    __syncthreads();
  }
  if (t < nb) partials[t] = part[t] - v;
}

__global__ __launch_bounds__(1024) void k_scan3(int* __restrict__ roff,
                                                int* __restrict__ cur,
                                                const int* __restrict__ partials,
                                                int nn, int netot) {
  int idx = blockIdx.x * 1024 + threadIdx.x;
  if (idx < nn) {
    int v = roff[idx] + partials[blockIdx.x];
    roff[idx] = v;
    cur[idx] = v;
  }
  if (idx == 0) roff[nn] = netot;
}

__global__ __launch_bounds__(256) void k_fill(const int* __restrict__ s1,
                                              const int* __restrict__ d1,
                                              const int* __restrict__ s2,
                                              const int* __restrict__ d2,
                                              int* __restrict__ cur,
                                              int* __restrict__ ssrc, int netot) {
  int e = blockIdx.x * blockDim.x + threadIdx.x;
  if (e >= netot) return;
  int s, d;
  if (e < NE) { s = s1[e]; d = d1[e]; }
  else        { s = s2[e - NE] + NN; d = d2[e - NE] + NN; }
  int p = atomicAdd(&cur[d], 1);
  ssrc[p] = s;
}

// ---------------- linear: hlin = xin @ W (+ attention dots) ----------------
// 64-row x 128-col tile per 128-thread block; thread = 8 rows x 8 cols
// (rows rr*8+ty so the 4 ty lane-groups per wave hit distinct LDS banks).
// Same grid (1563 blocks) as the 4x8 version but half the LDS reads per FMA
// and 2x the per-thread ILP. Layer 0: row n is embed[idx(n)] (fused gather).
__global__ __launch_bounds__(128) void k_linear(const float* __restrict__ xin,
                                                const int* __restrict__ iA,
                                                const int* __restrict__ iB,
                                                const float* __restrict__ W,
                                                const float* __restrict__ a_src,
                                                const float* __restrict__ a_dst,
                                                float* __restrict__ hlin,
                                                float* __restrict__ asrc,
                                                float* __restrict__ adst, int ntot) {
  __shared__ __align__(16) float w_lds[32 * 128];
  __shared__ __align__(16) float x_lds[64 * 36];
  __shared__ float red_s[256];
  __shared__ float red_d[256];
  const int t = threadIdx.x;           // 0..127
  const int tx = t & 15, ty = t >> 4;  // ty 0..7
  const int n0 = blockIdx.x * 64;

  float acc[8][8];
#pragma unroll
  for (int r = 0; r < 8; r++)
#pragma unroll
    for (int j = 0; j < 8; j++) acc[r][j] = 0.f;

  for (int kc = 0; kc < 128; kc += 32) {
#pragma unroll
    for (int i = 0; i < 8; i++) {
      int idx = i * 128 + t;  // 1024 float4 of W chunk
      int kr = idx >> 5, c4 = idx & 31;
      ((float4*)w_lds)[kr * 32 + c4] = ((const float4*)W)[(kc + kr) * 32 + c4];
    }
#pragma unroll
    for (int i = 0; i < 4; i++) {
      int idx = i * 128 + t;  // 512 float4 of x chunk (64 rows x 8 k4)
      int r = idx >> 3, k4 = idx & 7;
      int n = n0 + r;
      float4 v = make_float4(0.f, 0.f, 0.f, 0.f);
      if (n < ntot) {
        int row = n;
        if (iA) row = (n < NN) ? iA[n] : iB[n - NN];
        v = ((const float4*)xin)[(size_t)row * 32 + (kc >> 2) + k4];
      }
      *((float4*)&x_lds[r * 36 + k4 * 4]) = v;
    }
    __syncthreads();
#pragma unroll
    for (int kk = 0; kk < 32; kk += 4) {
      float4 xv[8];
#pragma unroll
      for (int rr = 0; rr < 8; rr++)
        xv[rr] = *((const float4*)&x_lds[(rr * 8 + ty) * 36 + kk]);
#pragma unroll
      for (int q = 0; q < 4; q++) {
        int k = kk + q;
        float4 w0 = ((const float4*)w_lds)[k * 32 + tx];
        float4 w1 = ((const float4*)w_lds)[k * 32 + 16 + tx];
#pragma unroll
        for (int rr = 0; rr < 8; rr++) {
          float xs = q == 0 ? xv[rr].x : q == 1 ? xv[rr].y : q == 2 ? xv[rr].z : xv[rr].w;
          acc[rr][0] += xs * w0.x;
          acc[rr][1] += xs * w0.y;
          acc[rr][2] += xs * w0.z;
          acc[rr][3] += xs * w0.w;
          acc[rr][4] += xs * w1.x;
          acc[rr][5] += xs * w1.y;
          acc[rr][6] += xs * w1.z;
          acc[rr][7] += xs * w1.w;
        }
      }
    }
    __syncthreads();
  }

  red_s[t] = 0.f; red_s[t + 128] = 0.f;
  red_d[t] = 0.f; red_d[t + 128] = 0.f;
  __syncthreads();
  const int hA = tx >> 3, hB = 2 + (tx >> 3);
#pragma unroll
  for (int rr = 0; rr < 8; rr++) {
    int r = rr * 8 + ty;
    int n = n0 + r;
    if (n < ntot) {
      float4 o0 = make_float4(acc[rr][0], acc[rr][1], acc[rr][2], acc[rr][3]);
      float4 o1 = make_float4(acc[rr][4], acc[rr][5], acc[rr][6], acc[rr][7]);
      ((float4*)hlin)[(size_t)n * 32 + tx] = o0;
      ((float4*)hlin)[(size_t)n * 32 + 16 + tx] = o1;
      float sA = 0.f, sB = 0.f, dA = 0.f, dB = 0.f;
#pragma unroll
      for (int j = 0; j < 4; j++) {
        sA += acc[rr][j] * a_src[tx * 4 + j];
        dA += acc[rr][j] * a_dst[tx * 4 + j];
        sB += acc[rr][4 + j] * a_src[64 + tx * 4 + j];
        dB += acc[rr][4 + j] * a_dst[64 + tx * 4 + j];
      }
      atomicAdd(&red_s[r * 4 + hA], sA);
      atomicAdd(&red_s[r * 4 + hB], sB);
      atomicAdd(&red_d[r * 4 + hA], dA);
      atomicAdd(&red_d[r * 4 + hB], dB);
    }
  }
  __syncthreads();
#pragma unroll
  for (int i = 0; i < 2; i++) {
    int idx = i * 128 + t;
    int r = idx >> 2, hd = idx & 3;
    int n = n0 + r;
    if (n < ntot) {
      asrc[n * 4 + hd] = red_s[idx];
      adst[n * 4 + hd] = red_d[idx];
    }
  }
}

// ---------------- aggregate v3: one wave per dst node, pair-split halves ----
__global__ __launch_bounds__(256) void k_aggregate(const float* __restrict__ hlin,
                                                   const float* __restrict__ asrcv,
                                                   const float* __restrict__ adstv,
                                                   const int* __restrict__ roff,
                                                   const int* __restrict__ ssrc,
                                                   const float* __restrict__ bias,
                                                   float* __restrict__ hout, int ntot) {
  const int lane = threadIdx.x & 63;
  const int n = blockIdx.x * 4 + (threadIdx.x >> 6);
  if (n >= ntot) return;
  const int p = lane >> 5;       // half: even/odd edge slots
  const int c = lane & 31;       // float4 column index within row
  const int hc = c >> 3;         // head of this lane's columns
  const int sub = lane & 15;     // staging edge slot
  const int hs = lane >> 4;      // staging head
  const int beg = roff[n], end = roff[n + 1];
  const int deg = end - beg;

  const float adh_hs = adstv[n * 4 + hs];
  const float pselfc = __expf(leaky(asrcv[n * 4 + hc] + adstv[n * 4 + hc]));

  float4 hv = ((const float4*)hlin)[(size_t)n * 32 + c];
  float4 acc;
  float dh;
  if (p == 0) {
    acc = make_float4(pselfc * hv.x, pselfc * hv.y, pselfc * hv.z, pselfc * hv.w);
    dh = pselfc;
  } else {
    acc = make_float4(0.f, 0.f, 0.f, 0.f);
    dh = 0.f;
  }

  for (int base = 0; base < deg; base += 16) {
    int cnt = deg - base; if (cnt > 16) cnt = 16;
    int s = n;        // invalid slots gather the (hot) self row with weight 0
    float px = 0.f;
    if (sub < cnt) {
      s = ssrc[beg + base + sub];
      px = __expf(leaky(asrcv[s * 4 + hs] + adh_hs));
    }
    int sj[8]; float ex[8]; float4 ld[8];
#pragma unroll
    for (int jj = 0; jj < 8; jj++) {
      int e = 2 * jj + p;
      sj[jj] = __shfl(s, e);
      ex[jj] = __shfl(px, hc * 16 + e);
      ld[jj] = ((const float4*)hlin)[(size_t)sj[jj] * 32 + c];
    }
#pragma unroll
    for (int jj = 0; jj < 8; jj++) {
      acc.x += ex[jj] * ld[jj].x;
      acc.y += ex[jj] * ld[jj].y;
      acc.z += ex[jj] * ld[jj].z;
      acc.w += ex[jj] * ld[jj].w;
      dh += ex[jj];
    }
  }

  acc.x += __shfl_xor(acc.x, 32);
  acc.y += __shfl_xor(acc.y, 32);
  acc.z += __shfl_xor(acc.z, 32);
  acc.w += __shfl_xor(acc.w, 32);
  dh += __shfl_xor(dh, 32);

  float inv = 1.f / (dh + GEPS);
  float4 bv = ((const float4*)bias)[c];
  if (p == 0) {
    float4 o;
    o.x = fmaxf(acc.x * inv + bv.x, 0.f);
    o.y = fmaxf(acc.y * inv + bv.y, 0.f);
    o.z = fmaxf(acc.z * inv + bv.z, 0.f);
    o.w = fmaxf(acc.w * inv + bv.w, 0.f);
    ((float4*)hout)[(size_t)n * 32 + c] = o;
  }
}

// ---------------- global attention pooling ----------------
__global__ __launch_bounds__(256) void k_pool(const float* __restrict__ h,
                                              const float* __restrict__ gate_w,
                                              const float* __restrict__ gate_b,
                                              float* __restrict__ acc_out) {
  const int lane = threadIdx.x & 63;
  const int widg = blockIdx.x * 4 + (threadIdx.x >> 6);
  const int nw = gridDim.x * 4;
  const float w0 = gate_w[lane * 2], w1 = gate_w[lane * 2 + 1];
  const float gb = gate_b[0];
  float acc0 = 0.f, acc1 = 0.f, se = 0.f;
  for (int n = widg; n < NN; n += nw) {
    float2 hv = ((const float2*)h)[(size_t)n * 64 + lane];
    float p = hv.x * w0 + hv.y * w1;
#pragma unroll
    for (int off = 1; off < 64; off <<= 1) p += __shfl_xor(p, off);
    float sg = 1.f / (1.f + __expf(-(p + gb)));
    float e = __expf(sg);
    se += e;
    acc0 += e * hv.x;
    acc1 += e * hv.y;
  }
  atomicAdd(&acc_out[lane * 2], acc0);
  atomicAdd(&acc_out[lane * 2 + 1], acc1);
  if (lane == 0) atomicAdd(&acc_out[128], se);
}

// ---------------- final MLP ----------------
__global__ __launch_bounds__(128) void k_mlp(const float* __restrict__ p1,
                                             const float* __restrict__ p2,
                                             const float* __restrict__ fc1_w,
                                             const float* __restrict__ fc1_b,
                                             const float* __restrict__ fc2_w,
                                             const float* __restrict__ fc2_b,
                                             float* __restrict__ out) {
  __shared__ float cat[256];
  __shared__ float red[2];
  const int t = threadIdx.x;
  cat[t] = p1[t] / p1[128];
  cat[128 + t] = p2[t] / p2[128];
  __syncthreads();
  float a = fc1_b[t];
  for (int k = 0; k < 256; k++) a += cat[k] * fc1_w[k * 128 + t];
  a = fmaxf(a, 0.f);
  float v = a * fc2_w[t];
#pragma unroll
  for (int off = 1; off < 64; off <<= 1) v += __shfl_xor(v, off);
  if ((t & 63) == 0) red[t >> 6] = v;
  __syncthreads();
  if (t == 0) out[0] = red[0] + red[1] + fc2_b[0];
}

extern "C" void kernel_launch(void* const* d_in, const int* in_sizes, int n_in,
                              void* d_out, int out_size, void* d_ws, size_t ws_size,
                              hipStream_t stream) {
  (void)in_sizes; (void)n_in; (void)out_size;
  const int* x1 = (const int*)d_in[0];
  const int* x2 = (const int*)d_in[1];
  const int* ei1 = (const int*)d_in[2];
  const int* ei2 = (const int*)d_in[3];
  const float* embed = (const float*)d_in[4];
  const float* W = (const float*)d_in[5];
  const float* attS = (const float*)d_in[6];
  const float* attD = (const float*)d_in[7];
  const float* bias = (const float*)d_in[8];
  const float* gw = (const float*)d_in[9];
  const float* gb = (const float*)d_in[10];
  const float* f1w = (const float*)d_in[11];
  const float* f1b = (const float*)d_in[12];
  const float* f2w = (const float*)d_in[13];
  const float* f2b = (const float*)d_in[14];
  float* out = (float*)d_out;

  auto req = [](int nt, int net) {
    size_t s = 0;
    auto pad = [&](size_t b) { s = (s + b + 255) & ~size_t(255); };
    pad(size_t(nt) * DIM * 4);
    pad(size_t(nt) * DIM * 4);
    pad(size_t(nt) * 16);
    pad(size_t(nt) * 16);
    pad(size_t(nt + 1) * 4);
    pad(size_t(nt) * 4);
    pad(size_t(net) * 4);
    pad(128 * 4);
    pad(2 * 129 * 4);
    return s;
  };
  const bool combined = ws_size >= req(2 * NN, 2 * NE);
  const int nt = combined ? 2 * NN : NN;
  const int net = combined ? 2 * NE : NE;

  char* ws = (char*)d_ws;
  size_t off = 0;
  auto alloc = [&](size_t bytes) {
    void* p = ws + off;
    off = (off + bytes + 255) & ~size_t(255);
    return p;
  };
  float* h_in = (float*)alloc(size_t(nt) * DIM * 4);
  float* h_lin = (float*)alloc(size_t(nt) * DIM * 4);
  float* asrc = (float*)alloc(size_t(nt) * 16);
  float* adst = (float*)alloc(size_t(nt) * 16);
  int* roff = (int*)alloc(size_t(nt + 1) * 4);
  int* cur = (int*)alloc(size_t(nt) * 4);
  int* ssrc = (int*)alloc(size_t(net) * 4);
  int* partials = (int*)alloc(128 * 4);
  float* pool = (float*)alloc(2 * 129 * 4);

  hipMemsetAsync(pool, 0, 2 * 129 * 4, stream);

  const int nb = (nt + 1023) / 1024;
  const int lgrid = (nt + 63) / 64;

  auto run_graphs = [&](const int* xA, const int* xB, const int* eA, const int* eB) {
    hipMemsetAsync(cur, 0, size_t(nt) * 4, stream);
    k_count<<<(net + 255) / 256, 256, 0, stream>>>(eA + NE, eB + NE, cur, net);
    k_scan1<<<nb, 1024, 0, stream>>>(cur, roff, partials, nt);
    k_scan2<<<1, 128, 0, stream>>>(partials, nb);
    k_scan3<<<nb, 1024, 0, stream>>>(roff, cur, partials, nt, net);
    k_fill<<<(net + 255) / 256, 256, 0, stream>>>(eA, eA + NE, eB, eB + NE, cur, ssrc, net);
    for (int l = 0; l < 3; ++l) {
      if (l == 0) {
        k_linear<<<lgrid, 128, 0, stream>>>(
            embed, xA, xB, W, attS, attD, h_lin, asrc, adst, nt);
      } else {
        k_linear<<<lgrid, 128, 0, stream>>>(
            h_in, nullptr, nullptr, W + l * DIM * DIM, attS + l * DIM, attD + l * DIM,
            h_lin, asrc, adst, nt);
      }
      k_aggregate<<<(nt + 3) / 4, 256, 0, stream>>>(
          h_lin, asrc, adst, roff, ssrc, bias + l * DIM, h_in, nt);
    }
  };

  if (combined) {
    run_graphs(x1, x2, ei1, ei2);
    k_pool<<<128, 256, 0, stream>>>(h_in, gw, gb, pool);
    k_pool<<<128, 256, 0, stream>>>(h_in + size_t(NN) * DIM, gw, gb, pool + 129);
  } else {
    run_graphs(x1, x1, ei1, ei1);
    k_pool<<<128, 256, 0, stream>>>(h_in, gw, gb, pool);
    run_graphs(x2, x2, ei2, ei2);
    k_pool<<<128, 256, 0, stream>>>(h_in, gw, gb, pool + 129);
  }
  k_mlp<<<1, 128, 0, stream>>>(pool, pool + 129, f1w, f1b, f2w, f2b, out);
}

// Round 8
// 704.709 us; speedup vs baseline: 1.3691x; 1.3691x over previous
//
#include <hip/hip_runtime.h>
#include <hip/hip_bf16.h>

#define NN 50000
#define NE 600000
#define DIM 128
#define VOCAB 30000
#define NEG 0.2f
#define GEPS 1e-16f

typedef __attribute__((ext_vector_type(8))) short bf16x8;
typedef __attribute__((ext_vector_type(4))) float f32x4;

__device__ __forceinline__ float leaky(float x) { return x > 0.f ? x : NEG * x; }

// bf16 split helpers (RNE)
__device__ __forceinline__ ushort f2bf(float f) {
  uint x = __float_as_uint(f);
  x += 0x7FFFu + ((x >> 16) & 1u);
  return (ushort)(x >> 16);
}
__device__ __forceinline__ float bf2f(ushort u) { return __uint_as_float(((uint)u) << 16); }

// ---------------- one-time: split embed into bf16 hi/lo ----------------
__global__ __launch_bounds__(256) void k_split(const float* __restrict__ src,
                                               ushort* __restrict__ hi,
                                               ushort* __restrict__ lo, int n4) {
  int i = blockIdx.x * 256 + threadIdx.x;
  if (i >= n4) return;
  float4 v = ((const float4*)src)[i];
  ushort4 h, l;
  h.x = f2bf(v.x); l.x = f2bf(v.x - bf2f(h.x));
  h.y = f2bf(v.y); l.y = f2bf(v.y - bf2f(h.y));
  h.z = f2bf(v.z); l.z = f2bf(v.z - bf2f(h.z));
  h.w = f2bf(v.w); l.w = f2bf(v.w - bf2f(h.w));
  ((ushort4*)hi)[i] = h;
  ((ushort4*)lo)[i] = l;
}

// ---------------- one-time: split W + pack into MFMA B-fragment order ------
// dst[((ll*8+ct)*4+kc)*64+lane][j] = W[ll][k=kc*32+(lane>>4)*8+j][n=ct*16+(lane&15)]
__global__ __launch_bounds__(256) void k_packw(const float* __restrict__ W,
                                               ushort* __restrict__ wph,
                                               ushort* __restrict__ wpl) {
  int i = blockIdx.x * 256 + threadIdx.x;
  if (i >= 3 * 128 * 128) return;
  int ll = i >> 14, rem = i & 16383, k = rem >> 7, n = rem & 127;
  float v = W[i];
  ushort h = f2bf(v), l = f2bf(v - bf2f(h));
  int ct = n >> 4, ln = n & 15, kc = k >> 5, kr = k & 31;
  int lane = (kr >> 3) * 16 + ln, j = kr & 7;
  size_t dst = ((((size_t)ll * 8 + ct) * 4 + kc) * 64 + lane) * 8 + j;
  wph[dst] = h;
  wpl[dst] = l;
}

// ---------------- CSR build ----------------
__global__ __launch_bounds__(256) void k_count(const int* __restrict__ d1,
                                               const int* __restrict__ d2,
                                               int* __restrict__ cnt, int netot) {
  int e = blockIdx.x * blockDim.x + threadIdx.x;
  if (e >= netot) return;
  int dst = (e < NE) ? d1[e] : d2[e - NE] + NN;
  atomicAdd(&cnt[dst], 1);
}

__global__ __launch_bounds__(1024) void k_scan1(const int* __restrict__ cnt,
                                                int* __restrict__ roff,
                                                int* __restrict__ partials, int nn) {
  __shared__ int part[1024];
  const int t = threadIdx.x;
  const int idx = blockIdx.x * 1024 + t;
  int v = (idx < nn) ? cnt[idx] : 0;
  part[t] = v;
  __syncthreads();
  for (int off = 1; off < 1024; off <<= 1) {
    int x = (t >= off) ? part[t - off] : 0;
    __syncthreads();
    part[t] += x;
    __syncthreads();
  }
  if (idx < nn) roff[idx] = part[t] - v;
  if (t == 1023) partials[blockIdx.x] = part[1023];
}

__global__ __launch_bounds__(128) void k_scan2(int* __restrict__ partials, int nb) {
  __shared__ int part[128];
  const int t = threadIdx.x;
  int v = (t < nb) ? partials[t] : 0;
  part[t] = v;
  __syncthreads();
  for (int off = 1; off < 128; off <<= 1) {
    int x = (t >= off) ? part[t - off] : 0;
    __syncthreads();
    part[t] += x;
    __syncthreads();
  }
  if (t < nb) partials[t] = part[t] - v;
}

__global__ __launch_bounds__(1024) void k_scan3(int* __restrict__ roff,
                                                int* __restrict__ cur,
                                                const int* __restrict__ partials,
                                                int nn, int netot) {
  int idx = blockIdx.x * 1024 + threadIdx.x;
  if (idx < nn) {
    int v = roff[idx] + partials[blockIdx.x];
    roff[idx] = v;
    cur[idx] = v;
  }
  if (idx == 0) roff[nn] = netot;
}

__global__ __launch_bounds__(256) void k_fill(const int* __restrict__ s1,
                                              const int* __restrict__ d1,
                                              const int* __restrict__ s2,
                                              const int* __restrict__ d2,
                                              int* __restrict__ cur,
                                              int* __restrict__ ssrc, int netot) {
  int e = blockIdx.x * blockDim.x + threadIdx.x;
  if (e >= netot) return;
  int s, d;
  if (e < NE) { s = s1[e]; d = d1[e]; }
  else        { s = s2[e - NE] + NN; d = d2[e - NE] + NN; }
  int p = atomicAdd(&cur[d], 1);
  ssrc[p] = s;
}

// ---------------- linear via split-bf16 MFMA ----------------
// hlin = (Ahi+Alo) @ (Whi+Wlo) ~= Ahi@Whi + Alo@Whi + Ahi@Wlo  (fp32 acc)
// wave = 16 rows x 128 cols; no LDS, no barriers. Layer 0: rows gathered from
// embed_hi/lo via iA/iB. Fragment layouts (m89-verified family):
//   A: m=lane&15, k=(lane>>4)*8+j  (16B contiguous per lane in row-major A)
//   B: n=lane&15, k=(lane>>4)*8+j  (pre-packed by k_packw)
//   D: col=lane&15, row=(lane>>4)*4+reg
__global__ __launch_bounds__(256) void k_linear(const ushort* __restrict__ Ahi,
                                                const ushort* __restrict__ Alo,
                                                const int* __restrict__ iA,
                                                const int* __restrict__ iB,
                                                const ushort* __restrict__ wph,
                                                const ushort* __restrict__ wpl,
                                                const float* __restrict__ a_src,
                                                const float* __restrict__ a_dst,
                                                float* __restrict__ hlin,
                                                float* __restrict__ asrc,
                                                float* __restrict__ adst, int ntot) {
  const int lane = threadIdx.x & 63;
  const int wv = threadIdx.x >> 6;
  const int m0 = blockIdx.x * 64 + wv * 16;
  const int ln = lane & 15, lh = lane >> 4;

  int m = m0 + ln;
  int mc = min(m, ntot - 1);
  int gr = mc;
  if (iA) gr = (mc < NN) ? iA[mc] : iB[mc - NN];
  const size_t abase = (size_t)gr * 128 + lh * 8;

  bf16x8 ah[4], al[4];
#pragma unroll
  for (int kc = 0; kc < 4; kc++) {
    ah[kc] = *(const bf16x8*)(Ahi + abase + kc * 32);
    al[kc] = *(const bf16x8*)(Alo + abase + kc * 32);
  }

  f32x4 acc[8];
#pragma unroll
  for (int ct = 0; ct < 8; ct++) acc[ct] = (f32x4){0.f, 0.f, 0.f, 0.f};

#pragma unroll
  for (int ct = 0; ct < 8; ct++) {
    const ushort* bh = wph + (size_t)ct * 2048 + lane * 8;
    const ushort* bl = wpl + (size_t)ct * 2048 + lane * 8;
#pragma unroll
    for (int kc = 0; kc < 4; kc++) {
      bf16x8 vh = *(const bf16x8*)(bh + kc * 512);
      bf16x8 vl = *(const bf16x8*)(bl + kc * 512);
      acc[ct] = __builtin_amdgcn_mfma_f32_16x16x32_bf16(ah[kc], vh, acc[ct], 0, 0, 0);
      acc[ct] = __builtin_amdgcn_mfma_f32_16x16x32_bf16(al[kc], vh, acc[ct], 0, 0, 0);
      acc[ct] = __builtin_amdgcn_mfma_f32_16x16x32_bf16(ah[kc], vl, acc[ct], 0, 0, 0);
    }
  }

  // C store: lane holds col=ct*16+ln for rows rbase+0..3
  const int rbase = m0 + lh * 4;
#pragma unroll
  for (int r = 0; r < 4; r++) {
    int row = rbase + r;
    if (row < ntot) {
      float* dst = hlin + (size_t)row * 128 + ln;
#pragma unroll
      for (int ct = 0; ct < 8; ct++) dst[ct * 16] = acc[ct][r];
    }
  }

  // attention dots: asrc[row][h] = sum_col hlin[row][col]*a_src[col]
  float av[8], dv[8];
#pragma unroll
  for (int ct = 0; ct < 8; ct++) {
    av[ct] = a_src[ct * 16 + ln];
    dv[ct] = a_dst[ct * 16 + ln];
  }
#pragma unroll
  for (int r = 0; r < 4; r++) {
    float s0 = 0.f, s1 = 0.f, s2 = 0.f, s3 = 0.f;
    float d0 = 0.f, d1 = 0.f, d2 = 0.f, d3 = 0.f;
#pragma unroll
    for (int ct = 0; ct < 8; ct++) {
      float x = acc[ct][r];
      if ((ct >> 1) == 0) { s0 += x * av[ct]; d0 += x * dv[ct]; }
      else if ((ct >> 1) == 1) { s1 += x * av[ct]; d1 += x * dv[ct]; }
      else if ((ct >> 1) == 2) { s2 += x * av[ct]; d2 += x * dv[ct]; }
      else { s3 += x * av[ct]; d3 += x * dv[ct]; }
    }
#pragma unroll
    for (int off = 1; off < 16; off <<= 1) {
      s0 += __shfl_xor(s0, off); s1 += __shfl_xor(s1, off);
      s2 += __shfl_xor(s2, off); s3 += __shfl_xor(s3, off);
      d0 += __shfl_xor(d0, off); d1 += __shfl_xor(d1, off);
      d2 += __shfl_xor(d2, off); d3 += __shfl_xor(d3, off);
    }
    int row = rbase + r;
    if (ln == 0 && row < ntot) {
      ((float4*)asrc)[row] = make_float4(s0, s1, s2, s3);
      ((float4*)adst)[row] = make_float4(d0, d1, d2, d3);
    }
  }
}

// ---------------- aggregate: one wave per dst node, pair-split halves ------
// Output written directly as bf16 hi/lo (input to next layer's MFMA).
__global__ __launch_bounds__(256) void k_aggregate(const float* __restrict__ hlin,
                                                   const float* __restrict__ asrcv,
                                                   const float* __restrict__ adstv,
                                                   const int* __restrict__ roff,
                                                   const int* __restrict__ ssrc,
                                                   const float* __restrict__ bias,
                                                   ushort* __restrict__ h_hi,
                                                   ushort* __restrict__ h_lo, int ntot) {
  const int lane = threadIdx.x & 63;
  const int n = blockIdx.x * 4 + (threadIdx.x >> 6);
  if (n >= ntot) return;
  const int p = lane >> 5;
  const int c = lane & 31;
  const int hc = c >> 3;
  const int sub = lane & 15;
  const int hs = lane >> 4;
  const int beg = roff[n], end = roff[n + 1];
  const int deg = end - beg;

  const float adh_hs = adstv[n * 4 + hs];
  const float pselfc = __expf(leaky(asrcv[n * 4 + hc] + adstv[n * 4 + hc]));

  float4 hv = ((const float4*)hlin)[(size_t)n * 32 + c];
  float4 acc;
  float dh;
  if (p == 0) {
    acc = make_float4(pselfc * hv.x, pselfc * hv.y, pselfc * hv.z, pselfc * hv.w);
    dh = pselfc;
  } else {
    acc = make_float4(0.f, 0.f, 0.f, 0.f);
    dh = 0.f;
  }

  for (int base = 0; base < deg; base += 16) {
    int cnt = deg - base; if (cnt > 16) cnt = 16;
    int s = n;
    float px = 0.f;
    if (sub < cnt) {
      s = ssrc[beg + base + sub];
      px = __expf(leaky(asrcv[s * 4 + hs] + adh_hs));
    }
    int sj[8]; float ex[8]; float4 ld[8];
#pragma unroll
    for (int jj = 0; jj < 8; jj++) {
      int e = 2 * jj + p;
      sj[jj] = __shfl(s, e);
      ex[jj] = __shfl(px, hc * 16 + e);
      ld[jj] = ((const float4*)hlin)[(size_t)sj[jj] * 32 + c];
    }
#pragma unroll
    for (int jj = 0; jj < 8; jj++) {
      acc.x += ex[jj] * ld[jj].x;
      acc.y += ex[jj] * ld[jj].y;
      acc.z += ex[jj] * ld[jj].z;
      acc.w += ex[jj] * ld[jj].w;
      dh += ex[jj];
    }
  }

  acc.x += __shfl_xor(acc.x, 32);
  acc.y += __shfl_xor(acc.y, 32);
  acc.z += __shfl_xor(acc.z, 32);
  acc.w += __shfl_xor(acc.w, 32);
  dh += __shfl_xor(dh, 32);

  float inv = 1.f / (dh + GEPS);
  float4 bv = ((const float4*)bias)[c];
  if (p == 0) {
    float4 o;
    o.x = fmaxf(acc.x * inv + bv.x, 0.f);
    o.y = fmaxf(acc.y * inv + bv.y, 0.f);
    o.z = fmaxf(acc.z * inv + bv.z, 0.f);
    o.w = fmaxf(acc.w * inv + bv.w, 0.f);
    ushort4 uh, ul;
    uh.x = f2bf(o.x); ul.x = f2bf(o.x - bf2f(uh.x));
    uh.y = f2bf(o.y); ul.y = f2bf(o.y - bf2f(uh.y));
    uh.z = f2bf(o.z); ul.z = f2bf(o.z - bf2f(uh.z));
    uh.w = f2bf(o.w); ul.w = f2bf(o.w - bf2f(uh.w));
    ((ushort4*)h_hi)[(size_t)n * 32 + c] = uh;
    ((ushort4*)h_lo)[(size_t)n * 32 + c] = ul;
  }
}

// ---------------- global attention pooling (reads bf16 hi/lo) ----------------
__global__ __launch_bounds__(256) void k_pool(const ushort* __restrict__ hh,
                                              const ushort* __restrict__ hl,
                                              const float* __restrict__ gate_w,
                                              const float* __restrict__ gate_b,
                                              float* __restrict__ acc_out) {
  const int lane = threadIdx.x & 63;
  const int widg = blockIdx.x * 4 + (threadIdx.x >> 6);
  const int nw = gridDim.x * 4;
  const float w0 = gate_w[lane * 2], w1 = gate_w[lane * 2 + 1];
  const float gb = gate_b[0];
  float acc0 = 0.f, acc1 = 0.f, se = 0.f;
  for (int n = widg; n < NN; n += nw) {
    ushort2 h2 = ((const ushort2*)hh)[(size_t)n * 64 + lane];
    ushort2 l2 = ((const ushort2*)hl)[(size_t)n * 64 + lane];
    float hx = bf2f(h2.x) + bf2f(l2.x);
    float hy = bf2f(h2.y) + bf2f(l2.y);
    float p = hx * w0 + hy * w1;
#pragma unroll
    for (int off = 1; off < 64; off <<= 1) p += __shfl_xor(p, off);
    float sg = 1.f / (1.f + __expf(-(p + gb)));
    float e = __expf(sg);
    se += e;
    acc0 += e * hx;
    acc1 += e * hy;
  }
  atomicAdd(&acc_out[lane * 2], acc0);
  atomicAdd(&acc_out[lane * 2 + 1], acc1);
  if (lane == 0) atomicAdd(&acc_out[128], se);
}

// ---------------- final MLP ----------------
__global__ __launch_bounds__(128) void k_mlp(const float* __restrict__ p1,
                                             const float* __restrict__ p2,
                                             const float* __restrict__ fc1_w,
                                             const float* __restrict__ fc1_b,
                                             const float* __restrict__ fc2_w,
                                             const float* __restrict__ fc2_b,
                                             float* __restrict__ out) {
  __shared__ float cat[256];
  __shared__ float red[2];
  const int t = threadIdx.x;
  cat[t] = p1[t] / p1[128];
  cat[128 + t] = p2[t] / p2[128];
  __syncthreads();
  float a = fc1_b[t];
  for (int k = 0; k < 256; k++) a += cat[k] * fc1_w[k * 128 + t];
  a = fmaxf(a, 0.f);
  float v = a * fc2_w[t];
#pragma unroll
  for (int off = 1; off < 64; off <<= 1) v += __shfl_xor(v, off);
  if ((t & 63) == 0) red[t >> 6] = v;
  __syncthreads();
  if (t == 0) out[0] = red[0] + red[1] + fc2_b[0];
}

extern "C" void kernel_launch(void* const* d_in, const int* in_sizes, int n_in,
                              void* d_out, int out_size, void* d_ws, size_t ws_size,
                              hipStream_t stream) {
  (void)in_sizes; (void)n_in; (void)out_size;
  const int* x1 = (const int*)d_in[0];
  const int* x2 = (const int*)d_in[1];
  const int* ei1 = (const int*)d_in[2];
  const int* ei2 = (const int*)d_in[3];
  const float* embed = (const float*)d_in[4];
  const float* W = (const float*)d_in[5];
  const float* attS = (const float*)d_in[6];
  const float* attD = (const float*)d_in[7];
  const float* bias = (const float*)d_in[8];
  const float* gw = (const float*)d_in[9];
  const float* gb = (const float*)d_in[10];
  const float* f1w = (const float*)d_in[11];
  const float* f1b = (const float*)d_in[12];
  const float* f2w = (const float*)d_in[13];
  const float* f2b = (const float*)d_in[14];
  float* out = (float*)d_out;

  auto req = [](int nt, int net) {
    size_t s = 0;
    auto pad = [&](size_t b) { s = (s + b + 255) & ~size_t(255); };
    pad(size_t(nt) * DIM * 2);        // h_hi
    pad(size_t(nt) * DIM * 2);        // h_lo
    pad(size_t(nt) * DIM * 4);        // h_lin
    pad(size_t(VOCAB) * DIM * 2);     // e_hi
    pad(size_t(VOCAB) * DIM * 2);     // e_lo
    pad(3 * 16384 * 2);               // wp_hi
    pad(3 * 16384 * 2);               // wp_lo
    pad(size_t(nt) * 16);             // asrc
    pad(size_t(nt) * 16);             // adst
    pad(size_t(nt + 1) * 4);          // roff
    pad(size_t(nt) * 4);              // cur
    pad(size_t(net) * 4);             // ssrc
    pad(128 * 4);                     // partials
    pad(2 * 129 * 4);                 // pool
    return s;
  };
  const bool combined = ws_size >= req(2 * NN, 2 * NE);
  const int nt = combined ? 2 * NN : NN;
  const int net = combined ? 2 * NE : NE;

  char* ws = (char*)d_ws;
  size_t off = 0;
  auto alloc = [&](size_t bytes) {
    void* p = ws + off;
    off = (off + bytes + 255) & ~size_t(255);
    return p;
  };
  ushort* h_hi = (ushort*)alloc(size_t(nt) * DIM * 2);
  ushort* h_lo = (ushort*)alloc(size_t(nt) * DIM * 2);
  float* h_lin = (float*)alloc(size_t(nt) * DIM * 4);
  ushort* e_hi = (ushort*)alloc(size_t(VOCAB) * DIM * 2);
  ushort* e_lo = (ushort*)alloc(size_t(VOCAB) * DIM * 2);
  ushort* wp_hi = (ushort*)alloc(3 * 16384 * 2);
  ushort* wp_lo = (ushort*)alloc(3 * 16384 * 2);
  float* asrc = (float*)alloc(size_t(nt) * 16);
  float* adst = (float*)alloc(size_t(nt) * 16);
  int* roff = (int*)alloc(size_t(nt + 1) * 4);
  int* cur = (int*)alloc(size_t(nt) * 4);
  int* ssrc = (int*)alloc(size_t(net) * 4);
  int* partials = (int*)alloc(128 * 4);
  float* pool = (float*)alloc(2 * 129 * 4);

  hipMemsetAsync(pool, 0, 2 * 129 * 4, stream);

  // one-time preprocessing
  const int esplit4 = VOCAB * DIM / 4;
  k_split<<<(esplit4 + 255) / 256, 256, 0, stream>>>(embed, e_hi, e_lo, esplit4);
  k_packw<<<(3 * 128 * 128 + 255) / 256, 256, 0, stream>>>(W, wp_hi, wp_lo);

  const int nb = (nt + 1023) / 1024;
  const int lgrid = (nt + 63) / 64;

  auto run_graphs = [&](const int* xA, const int* xB, const int* eA, const int* eB) {
    hipMemsetAsync(cur, 0, size_t(nt) * 4, stream);
    k_count<<<(net + 255) / 256, 256, 0, stream>>>(eA + NE, eB + NE, cur, net);
    k_scan1<<<nb, 1024, 0, stream>>>(cur, roff, partials, nt);
    k_scan2<<<1, 128, 0, stream>>>(partials, nb);
    k_scan3<<<nb, 1024, 0, stream>>>(roff, cur, partials, nt, net);
    k_fill<<<(net + 255) / 256, 256, 0, stream>>>(eA, eA + NE, eB, eB + NE, cur, ssrc, net);
    for (int l = 0; l < 3; ++l) {
      if (l == 0) {
        k_linear<<<lgrid, 256, 0, stream>>>(
            e_hi, e_lo, xA, xB, wp_hi, wp_lo, attS, attD, h_lin, asrc, adst, nt);
      } else {
        k_linear<<<lgrid, 256, 0, stream>>>(
            h_hi, h_lo, nullptr, nullptr, wp_hi + l * 16384, wp_lo + l * 16384,
            attS + l * DIM, attD + l * DIM, h_lin, asrc, adst, nt);
      }
      k_aggregate<<<(nt + 3) / 4, 256, 0, stream>>>(
          h_lin, asrc, adst, roff, ssrc, bias + l * DIM, h_hi, h_lo, nt);
    }
  };

  if (combined) {
    run_graphs(x1, x2, ei1, ei2);
    k_pool<<<128, 256, 0, stream>>>(h_hi, h_lo, gw, gb, pool);
    k_pool<<<128, 256, 0, stream>>>(h_hi + size_t(NN) * DIM, h_lo + size_t(NN) * DIM,
                                    gw, gb, pool + 129);
  } else {
    run_graphs(x1, x1, ei1, ei1);
    k_pool<<<128, 256, 0, stream>>>(h_hi, h_lo, gw, gb, pool);
    run_graphs(x2, x2, ei2, ei2);
    k_pool<<<128, 256, 0, stream>>>(h_hi, h_lo, gw, gb, pool + 129);
  }
  k_mlp<<<1, 128, 0, stream>>>(pool, pool + 129, f1w, f1b, f2w, f2b, out);
}